// Round 4
// baseline (322.729 us; speedup 1.0000x reference)
//
#include <hip/hip_runtime.h>
#include <hip/hip_bf16.h>

typedef __bf16 bf16;
typedef __bf16 bf16x8 __attribute__((ext_vector_type(8)));
typedef float  f32x4  __attribute__((ext_vector_type(4)));

#define LOG2E 1.44269504088896340736f

// ---------------------------------------------------------------------------
// fp32 -> bf16 conversion. Grid: (2048, 5). blockIdx.y selects tensor:
// 0 = x (4M elems, all 2048 x-blocks), 1..4 = Wq,Wk,Wv,Wo (1M elems, 512 blocks).
// Each thread converts 8 elements (2x float4 in, 1x 16B bf16x8 out).
// ---------------------------------------------------------------------------
__global__ void cvt_f32_bf16(
    const float* __restrict__ s0, const float* __restrict__ s1,
    const float* __restrict__ s2, const float* __restrict__ s3,
    const float* __restrict__ s4,
    bf16* __restrict__ d0, bf16* __restrict__ d1, bf16* __restrict__ d2,
    bf16* __restrict__ d3, bf16* __restrict__ d4)
{
    const float* s; bf16* d; int nblk;
    switch (blockIdx.y) {
        case 0:  s = s0; d = d0; nblk = 2048; break;
        case 1:  s = s1; d = d1; nblk = 512;  break;
        case 2:  s = s2; d = d2; nblk = 512;  break;
        case 3:  s = s3; d = d3; nblk = 512;  break;
        default: s = s4; d = d4; nblk = 512;  break;
    }
    if ((int)blockIdx.x >= nblk) return;
    int idx = blockIdx.x * 256 + threadIdx.x;      // one 8-elem chunk per thread
    float4 a = ((const float4*)s)[idx * 2];
    float4 b = ((const float4*)s)[idx * 2 + 1];
    bf16x8 o;
    o[0] = (bf16)a.x; o[1] = (bf16)a.y; o[2] = (bf16)a.z; o[3] = (bf16)a.w;
    o[4] = (bf16)b.x; o[5] = (bf16)b.y; o[6] = (bf16)b.z; o[7] = (bf16)b.w;
    *(bf16x8*)&d[idx * 8] = o;
}

// ---------------------------------------------------------------------------
// C[M,N] = A[M,K] @ B[N,K]^T  (both K-major / "BT" layout), bf16 in, CT out.
// mode 0: C[m*N + n] (+ optional fp32 bias[n])
// mode 1: transposed per-head scatter for V: C[((m>>11)*1024 + n)*2048 + (m&2047)]
// 128x128 tile, BK=32, 256 threads = 4 waves in 2x2, each wave 64x64 (4x4 MFMA).
// ---------------------------------------------------------------------------
template <typename CT>
__global__ __launch_bounds__(256, 2) void gemm_bt(
    const bf16* __restrict__ A, const bf16* __restrict__ B,
    CT* __restrict__ C, const float* __restrict__ bias,
    int M, int N, int K, int mode)
{
    __shared__ bf16 sA[128 * 32];   // 8 KB, row-major [row][k]
    __shared__ bf16 sB[128 * 32];   // 8 KB

    const int tid  = threadIdx.x;
    const int lane = tid & 63;
    const int w    = tid >> 6;          // wave 0..3
    const int wr   = w >> 1, wc = w & 1;
    const int r    = lane & 15;         // MFMA m/n lane index
    const int qd   = lane >> 4;         // MFMA k-quad
    const int m0   = blockIdx.y * 128;
    const int n0   = blockIdx.x * 128;

    f32x4 acc[4][4];
    const f32x4 zero4 = {0.f, 0.f, 0.f, 0.f};
#pragma unroll
    for (int mi = 0; mi < 4; ++mi)
#pragma unroll
        for (int ni = 0; ni < 4; ++ni) acc[mi][ni] = zero4;

    const int nkt = K >> 5;
    for (int kt = 0; kt < nkt; ++kt) {
        const bf16* gA = A + (size_t)m0 * K + kt * 32;
        const bf16* gB = B + (size_t)n0 * K + kt * 32;
        bf16x8 ra[2], rb[2];
        int rowv[2], chv[2];
#pragma unroll
        for (int j = 0; j < 2; ++j) {
            int task = j * 256 + tid;          // 0..511 : row = task>>2, 16B-chunk = task&3
            rowv[j] = task >> 2; chv[j] = task & 3;
            ra[j] = *(const bf16x8*)&gA[(size_t)rowv[j] * K + chv[j] * 8];
            rb[j] = *(const bf16x8*)&gB[(size_t)rowv[j] * K + chv[j] * 8];
        }
        __syncthreads();   // previous iteration's LDS frag reads complete
#pragma unroll
        for (int j = 0; j < 2; ++j) {
            *(bf16x8*)&sA[rowv[j] * 32 + chv[j] * 8] = ra[j];
            *(bf16x8*)&sB[rowv[j] * 32 + chv[j] * 8] = rb[j];
        }
        __syncthreads();   // staging visible to all waves

        bf16x8 af[4], bfr[4];
#pragma unroll
        for (int mi = 0; mi < 4; ++mi)
            af[mi] = *(const bf16x8*)&sA[(wr * 64 + mi * 16 + r) * 32 + qd * 8];
#pragma unroll
        for (int ni = 0; ni < 4; ++ni)
            bfr[ni] = *(const bf16x8*)&sB[(wc * 64 + ni * 16 + r) * 32 + qd * 8];
#pragma unroll
        for (int mi = 0; mi < 4; ++mi)
#pragma unroll
            for (int ni = 0; ni < 4; ++ni)
                acc[mi][ni] = __builtin_amdgcn_mfma_f32_16x16x32_bf16(
                    af[mi], bfr[ni], acc[mi][ni], 0, 0, 0);
    }

    // epilogue: C/D layout col = lane&15, row = (lane>>4)*4 + reg
#pragma unroll
    for (int mi = 0; mi < 4; ++mi)
#pragma unroll
        for (int ni = 0; ni < 4; ++ni)
#pragma unroll
            for (int i = 0; i < 4; ++i) {
                int row = m0 + wr * 64 + mi * 16 + qd * 4 + i;
                int col = n0 + wc * 64 + ni * 16 + r;
                float v = acc[mi][ni][i];
                if (bias) v += bias[col];
                if (mode == 0) {
                    C[(size_t)row * N + col] = (CT)v;
                } else {
                    // vT[(b*16+h)*64 + p][s] ; b = row>>11, s = row&2047, col = h*64+p
                    C[((size_t)((row >> 11) * 1024 + col)) * 2048 + (row & 2047)] = (CT)v;
                }
            }
}

// ---------------------------------------------------------------------------
// Fused flash attention. Grid: (S/128=16, B*H=32), 256 threads (4 waves).
// Wave w owns q-rows [32w, 32w+32). K/V tiles of 64 keys, online softmax with
// per-lane m/l state (row = 32w + 16mi + 4*(lane>>4) + i in BOTH S and O
// accumulator layouts, so no cross-wave softmax traffic).
// ---------------------------------------------------------------------------
__global__ __launch_bounds__(256, 2) void attn_kernel(
    const bf16* __restrict__ qbuf, const bf16* __restrict__ kbuf,
    const bf16* __restrict__ vT, bf16* __restrict__ concat)
{
    __shared__ bf16 sQ[128 * 80];   // 20 KB, q-rows x 64 p (pad 64->80)
    __shared__ bf16 sK[64 * 80];    // 10 KB, t-rows x 64 p
    __shared__ bf16 sV[64 * 80];    // 10 KB, p-rows x 64 t
    __shared__ bf16 sP[128 * 80];   // 20 KB, q-rows x 64 t
    // total 60 KB -> 2 blocks/CU

    const int tid  = threadIdx.x;
    const int lane = tid & 63;
    const int w    = tid >> 6;
    const int r    = lane & 15;
    const int qd   = lane >> 4;
    const int qt   = blockIdx.x;        // 0..15
    const int bh   = blockIdx.y;        // 0..31
    const int b    = bh >> 4, h = bh & 15;
    const int qrow0 = b * 2048 + qt * 128;      // global row in [0,4096)
    const size_t vbase = (size_t)bh * 64 * 2048;

    // stage Q once: 128 rows x 64
#pragma unroll
    for (int t = 0; t < 4; ++t) {
        int flat = t * 256 + tid;            // 0..1023
        int row = flat >> 3, ch = flat & 7;
        bf16x8 val = *(const bf16x8*)&qbuf[(size_t)(qrow0 + row) * 1024 + h * 64 + ch * 8];
        *(bf16x8*)&sQ[row * 80 + ch * 8] = val;
    }

    float m_st[2][4], l_st[2][4];
    f32x4 acc_o[2][4];
    const f32x4 zero4 = {0.f, 0.f, 0.f, 0.f};
#pragma unroll
    for (int mi = 0; mi < 2; ++mi)
#pragma unroll
        for (int i = 0; i < 4; ++i) { m_st[mi][i] = -INFINITY; l_st[mi][i] = 0.f; }
#pragma unroll
    for (int mi = 0; mi < 2; ++mi)
#pragma unroll
        for (int nj = 0; nj < 4; ++nj) acc_o[mi][nj] = zero4;

    for (int tt = 0; tt < 32; ++tt) {
        // global loads to registers first (overlap with prior compute)
        bf16x8 rk[2], rv[2];
        int krow[2], kch[2];
#pragma unroll
        for (int t = 0; t < 2; ++t) {
            int flat = t * 256 + tid;        // 0..511
            krow[t] = flat >> 3; kch[t] = flat & 7;
            rk[t] = *(const bf16x8*)&kbuf[(size_t)(b * 2048 + tt * 64 + krow[t]) * 1024 + h * 64 + kch[t] * 8];
            rv[t] = *(const bf16x8*)&vT[vbase + (size_t)krow[t] * 2048 + tt * 64 + kch[t] * 8];
        }
        __syncthreads();   // prev iteration's sK/sV reads complete (covers sQ staging on tt=0)
#pragma unroll
        for (int t = 0; t < 2; ++t) {
            *(bf16x8*)&sK[krow[t] * 80 + kch[t] * 8] = rk[t];
            *(bf16x8*)&sV[krow[t] * 80 + kch[t] * 8] = rv[t];
        }
        __syncthreads();

        // S = Q K^T  (M=32 rows for this wave, N=64 keys, K=64)
        f32x4 accs[2][4];
#pragma unroll
        for (int mi = 0; mi < 2; ++mi)
#pragma unroll
            for (int ni = 0; ni < 4; ++ni) accs[mi][ni] = zero4;
#pragma unroll
        for (int ks = 0; ks < 2; ++ks) {
            bf16x8 aq[2];
#pragma unroll
            for (int mi = 0; mi < 2; ++mi)
                aq[mi] = *(const bf16x8*)&sQ[(w * 32 + mi * 16 + r) * 80 + ks * 32 + qd * 8];
#pragma unroll
            for (int ni = 0; ni < 4; ++ni) {
                bf16x8 bk = *(const bf16x8*)&sK[(ni * 16 + r) * 80 + ks * 32 + qd * 8];
#pragma unroll
                for (int mi = 0; mi < 2; ++mi)
                    accs[mi][ni] = __builtin_amdgcn_mfma_f32_16x16x32_bf16(
                        aq[mi], bk, accs[mi][ni], 0, 0, 0);
            }
        }
#pragma unroll
        for (int mi = 0; mi < 2; ++mi)
#pragma unroll
            for (int ni = 0; ni < 4; ++ni) accs[mi][ni] *= 0.125f;  // 1/sqrt(64)

        // online softmax per row (row = 32w + 16mi + 4qd + i)
#pragma unroll
        for (int mi = 0; mi < 2; ++mi)
#pragma unroll
            for (int i = 0; i < 4; ++i) {
                float mx = accs[mi][0][i];
#pragma unroll
                for (int ni = 1; ni < 4; ++ni) mx = fmaxf(mx, accs[mi][ni][i]);
#pragma unroll
                for (int xm = 1; xm < 16; xm <<= 1) mx = fmaxf(mx, __shfl_xor(mx, xm, 64));
                float mnew = fmaxf(m_st[mi][i], mx);
                float sum = 0.f;
#pragma unroll
                for (int ni = 0; ni < 4; ++ni) {
                    float p = exp2f((accs[mi][ni][i] - mnew) * LOG2E);
                    accs[mi][ni][i] = p;
                    sum += p;
                }
#pragma unroll
                for (int xm = 1; xm < 16; xm <<= 1) sum += __shfl_xor(sum, xm, 64);
                float alpha = exp2f((m_st[mi][i] - mnew) * LOG2E);
                l_st[mi][i] = l_st[mi][i] * alpha + sum;
                m_st[mi][i] = mnew;
#pragma unroll
                for (int nj = 0; nj < 4; ++nj) acc_o[mi][nj][i] *= alpha;
                int prow = w * 32 + mi * 16 + qd * 4 + i;
#pragma unroll
                for (int ni = 0; ni < 4; ++ni)
                    sP[prow * 80 + ni * 16 + r] = (bf16)accs[mi][ni][i];
            }

        __syncthreads();   // make sP writes visible before PV reads

        // O += P V
#pragma unroll
        for (int ks = 0; ks < 2; ++ks) {
            bf16x8 ap[2];
#pragma unroll
            for (int mi = 0; mi < 2; ++mi)
                ap[mi] = *(const bf16x8*)&sP[(w * 32 + mi * 16 + r) * 80 + ks * 32 + qd * 8];
#pragma unroll
            for (int nj = 0; nj < 4; ++nj) {
                bf16x8 bv = *(const bf16x8*)&sV[(nj * 16 + r) * 80 + ks * 32 + qd * 8];
#pragma unroll
                for (int mi = 0; mi < 2; ++mi)
                    acc_o[mi][nj] = __builtin_amdgcn_mfma_f32_16x16x32_bf16(
                        ap[mi], bv, acc_o[mi][nj], 0, 0, 0);
            }
        }
    }

    // epilogue: O / l -> concat[m, h*64+p] (bf16)
#pragma unroll
    for (int mi = 0; mi < 2; ++mi)
#pragma unroll
        for (int i = 0; i < 4; ++i) {
            float inv  = 1.0f / l_st[mi][i];
            int rowl   = w * 32 + mi * 16 + qd * 4 + i;
            int grow   = qrow0 + rowl;
#pragma unroll
            for (int nj = 0; nj < 4; ++nj) {
                int gcol = h * 64 + nj * 16 + r;
                concat[(size_t)grow * 1024 + gcol] = (bf16)(acc_o[mi][nj][i] * inv);
            }
        }
}

// ---------------------------------------------------------------------------
extern "C" void kernel_launch(void* const* d_in, const int* in_sizes, int n_in,
                              void* d_out, int out_size, void* d_ws, size_t ws_size,
                              hipStream_t stream)
{
    // Inputs fp32 (verified round 3: fp32 reads -> finite). Output: fp32
    // (the reference's output dtype, per the harness contract).
    const float* x  = (const float*)d_in[0];   // [4096, 1024]
    const float* Wq = (const float*)d_in[1];   // [1024, 1024] (row = out feature)
    const float* Wk = (const float*)d_in[2];
    const float* Wv = (const float*)d_in[3];
    const float* Wo = (const float*)d_in[4];
    const float* bo = (const float*)d_in[5];   // [1024]
    float* out = (float*)d_out;

    char* ws = (char*)d_ws;
    bf16* xb     = (bf16*)(ws);               // 8 MB  [4096][1024]
    bf16* Wqb    = (bf16*)(ws + (8u  << 20)); // 2 MB
    bf16* Wkb    = (bf16*)(ws + (10u << 20));
    bf16* Wvb    = (bf16*)(ws + (12u << 20));
    bf16* Wob    = (bf16*)(ws + (14u << 20));
    bf16* qbuf   = (bf16*)(ws + (16u << 20)); // 8 MB [4096][1024]
    bf16* kbuf   = (bf16*)(ws + (24u << 20)); // 8 MB
    bf16* vT     = (bf16*)(ws + (32u << 20)); // 8 MB [32][64][2048] = [b,h][p][s]
    bf16* concat = (bf16*)(ws + (40u << 20)); // 8 MB [4096][1024]

    hipLaunchKernelGGL(cvt_f32_bf16, dim3(2048, 5), dim3(256), 0, stream,
                       x, Wq, Wk, Wv, Wo, xb, Wqb, Wkb, Wvb, Wob);

    dim3 gg(8, 32), bb(256);
    hipLaunchKernelGGL((gemm_bt<bf16>),  gg, bb, 0, stream, xb, Wqb, qbuf, (const float*)nullptr, 4096, 1024, 1024, 0);
    hipLaunchKernelGGL((gemm_bt<bf16>),  gg, bb, 0, stream, xb, Wkb, kbuf, (const float*)nullptr, 4096, 1024, 1024, 0);
    hipLaunchKernelGGL((gemm_bt<bf16>),  gg, bb, 0, stream, xb, Wvb, vT,   (const float*)nullptr, 4096, 1024, 1024, 1);
    hipLaunchKernelGGL(attn_kernel, dim3(16, 32), bb, 0, stream, qbuf, kbuf, vT, concat);
    hipLaunchKernelGGL((gemm_bt<float>), gg, bb, 0, stream, concat, Wob, out, bo, 4096, 1024, 1024, 0);
}